// Round 10
// baseline (282.762 us; speedup 1.0000x reference)
//
#include <hip/hip_runtime.h>
#include <math.h>

#define G    4      // segments per block
#define CAP  96     // max staged rows per group (mean 80; ~4% fallback to HBM path)

#define FMA4(A, s, Mv) do { (A).x += (s)*(Mv).x; (A).y += (s)*(Mv).y; \
                            (A).z += (s)*(Mv).z; (A).w += (s)*(Mv).w; } while (0)

// ---------------------------------------------------------------------------
__global__ void k_segstarts(const int* __restrict__ map, int* __restrict__ starts,
                            int V, int S) {
    int i = blockIdx.x * blockDim.x + threadIdx.x;
    if (i >= V) return;
    int cur  = map[i];
    int prev = (i == 0) ? -1 : map[i - 1];
    for (int s = prev + 1; s <= cur; ++s) starts[s] = i;
    if (i == V - 1) {
        for (int s = cur + 1; s <= S; ++s) starts[s] = V;
    }
}

// M[i][j] = sum_h Wk[h][i]*Wv[h][j] ;  Wt[i][o] = Wo[o][i]
__global__ void k_prep(const float* __restrict__ Wk, const float* __restrict__ Wv,
                       const float* __restrict__ Wo,
                       float* __restrict__ M, float* __restrict__ Wt) {
    int i = blockIdx.x;
    int j = threadIdx.x;
    float acc = 0.f;
#pragma unroll 8
    for (int h = 0; h < 128; ++h)
        acc += Wk[h * 128 + i] * Wv[h * 128 + j];
    M[i * 128 + j]  = acc;
    Wt[i * 128 + j] = Wo[j * 128 + i];
}

// ---------------------------------------------------------------------------
// k_main: one block = G consecutive segments = one contiguous fp32 row range
// staged once into LDS. ONE barrier (after stage); all later phases are
// wave-local (same-wave LDS write->read needs no __syncthreads):
//   mean(w) -> sE[w] -> qGEMM (q kept in registers: lane map jq == attn's c)
//   -> attn -> sE[w] -> outGEMM -> global.
// GEMMs: float4 operand loads, 16 in flight per batch, i-split + 1 shfl.
// ---------------------------------------------------------------------------
__global__ __launch_bounds__(256, 3) void k_main(
    const float* __restrict__ E, const int* __restrict__ starts,
    const float* __restrict__ M, const float* __restrict__ Wt,
    float* __restrict__ out, int V, int S)
{
    __shared__ float sA[CAP][128];   // 48 KB staged rows
    __shared__ float sE[G][128];     // ebar, later etilde (2 KB)

    const int tid  = threadIdx.x;
    const int w    = tid >> 6;       // wave id = local segment id
    const int lane = tid & 63;
    const int s0   = blockIdx.x * G;

    const int se    = min(s0 + G, S);
    const int gr0   = starts[s0];
    const int nrows = starts[se] - gr0;
    const bool staged = (nrows <= CAP);

    const int c  = lane & 31;        // column quad (attn) == GEMM j-quad
    const int g  = lane >> 5;        // row parity (sweeps) == GEMM i-half

    // ---------------- stage: E rows -> LDS (one barrier after) -------------
    if (staged && nrows > 0) {
        const int q4 = tid & 31;
        const int rr = tid >> 5;                 // 0..7, stride 8
        const float* gp = E + (size_t)gr0 * 128 + q4 * 4;
        float4 t[12];
#pragma unroll
        for (int k = 0; k < 12; ++k) {
            const int r = min(rr + k * 8, nrows - 1);   // clamp: benign dup
            t[k] = *(const float4*)(gp + (size_t)r * 128);
        }
#pragma unroll
        for (int k = 0; k < 12; ++k)
            *(float4*)&sA[rr + k * 8][q4 * 4] = t[k];   // dup rows unread
    }
    __syncthreads();                 // the ONLY block-wide barrier

    // per-wave segment meta
    const int segi = s0 + w;
    int r0 = 0, n = 0, off = 0;
    if (segi < S) {
        r0  = starts[segi];
        n   = starts[segi + 1] - r0;
        off = r0 - gr0;
    }

    // ---------------- mean: ebar[w] (wave-local) ---------------------------
    {
        float4 sum = make_float4(0.f, 0.f, 0.f, 0.f);
        if (segi < S && n > 0) {
            if (staged) {
#pragma unroll 4
                for (int rp = 0; rp < n; rp += 2) {
                    const int row = rp + g;
                    const int rcl = min(row, n - 1);
                    const float4 ev = *(const float4*)&sA[off + rcl][c * 4];
                    const float m = (row < n) ? 1.f : 0.f;
                    sum.x += m * ev.x; sum.y += m * ev.y;
                    sum.z += m * ev.z; sum.w += m * ev.w;
                }
            } else {
                const float* bp = E + (size_t)r0 * 128 + c * 4;
#pragma unroll 4
                for (int rp = 0; rp < n; rp += 2) {
                    const int row = rp + g;
                    const int rcl = min(row, n - 1);
                    const float4 ev = *(const float4*)(bp + (size_t)rcl * 128);
                    const float m = (row < n) ? 1.f : 0.f;
                    sum.x += m * ev.x; sum.y += m * ev.y;
                    sum.z += m * ev.z; sum.w += m * ev.w;
                }
            }
            sum.x += __shfl_xor(sum.x, 32);
            sum.y += __shfl_xor(sum.y, 32);
            sum.z += __shfl_xor(sum.z, 32);
            sum.w += __shfl_xor(sum.w, 32);
            const float inv = 1.0f / (float)n;
            sum.x *= inv; sum.y *= inv; sum.z *= inv; sum.w *= inv;
        }
        if (g == 0)
            *(float4*)&sE[w][c * 4] = sum;    // zeros when segi>=S or n==0
    }
    // no barrier: sE[w] is wave-private; same-wave write->read is ordered

    // ---------------- q GEMM (wave-local, q stays in registers) ------------
    float4 qv;
    {
        const float4* Mb4 = (const float4*)M + (size_t)g * 64 * 32 + c;
        const float4* se4 = (const float4*)&sE[w][g * 64];
        float4 a = make_float4(0.f, 0.f, 0.f, 0.f);
#pragma unroll
        for (int b = 0; b < 4; ++b) {
            float4 m4[16];
#pragma unroll
            for (int k = 0; k < 16; ++k)
                m4[k] = Mb4[(size_t)(b * 16 + k) * 32];
            const float4 e0 = se4[b * 4 + 0];
            const float4 e1 = se4[b * 4 + 1];
            const float4 e2 = se4[b * 4 + 2];
            const float4 e3 = se4[b * 4 + 3];
            FMA4(a, e0.x, m4[0]);  FMA4(a, e0.y, m4[1]);
            FMA4(a, e0.z, m4[2]);  FMA4(a, e0.w, m4[3]);
            FMA4(a, e1.x, m4[4]);  FMA4(a, e1.y, m4[5]);
            FMA4(a, e1.z, m4[6]);  FMA4(a, e1.w, m4[7]);
            FMA4(a, e2.x, m4[8]);  FMA4(a, e2.y, m4[9]);
            FMA4(a, e2.z, m4[10]); FMA4(a, e2.w, m4[11]);
            FMA4(a, e3.x, m4[12]); FMA4(a, e3.y, m4[13]);
            FMA4(a, e3.z, m4[14]); FMA4(a, e3.w, m4[15]);
        }
        a.x += __shfl_xor(a.x, 32);          // both i-halves -> full q quad
        a.y += __shfl_xor(a.y, 32);
        a.z += __shfl_xor(a.z, 32);
        a.w += __shfl_xor(a.w, 32);
        qv = a;                              // lane map == attn's (c)
    }

    // ---------------- attn: merged scores + exp + weighted sum -------------
    {
        float4 acc = make_float4(0.f, 0.f, 0.f, 0.f);
        float Z = 0.f;
        if (segi < S && n > 0) {
            if (staged) {
#pragma unroll 4
                for (int rp = 0; rp < n; rp += 2) {
                    const int row = rp + g;
                    const int rcl = min(row, n - 1);
                    const float4 ev = *(const float4*)&sA[off + rcl][c * 4];
                    float pd = ev.x * qv.x + ev.y * qv.y
                             + ev.z * qv.z + ev.w * qv.w;
                    pd += __shfl_xor(pd, 1);
                    pd += __shfl_xor(pd, 2);
                    pd += __shfl_xor(pd, 4);
                    pd += __shfl_xor(pd, 8);
                    pd += __shfl_xor(pd, 16);
                    const float wgt = (row < n) ? __expf(pd) : 0.f;
                    Z += wgt;
                    acc.x += wgt * ev.x; acc.y += wgt * ev.y;
                    acc.z += wgt * ev.z; acc.w += wgt * ev.w;
                }
            } else {
                const float* bp = E + (size_t)r0 * 128 + c * 4;
#pragma unroll 4
                for (int rp = 0; rp < n; rp += 2) {
                    const int row = rp + g;
                    const int rcl = min(row, n - 1);
                    const float4 ev = *(const float4*)(bp + (size_t)rcl * 128);
                    float pd = ev.x * qv.x + ev.y * qv.y
                             + ev.z * qv.z + ev.w * qv.w;
                    pd += __shfl_xor(pd, 1);
                    pd += __shfl_xor(pd, 2);
                    pd += __shfl_xor(pd, 4);
                    pd += __shfl_xor(pd, 8);
                    pd += __shfl_xor(pd, 16);
                    const float wgt = (row < n) ? __expf(pd) : 0.f;
                    Z += wgt;
                    acc.x += wgt * ev.x; acc.y += wgt * ev.y;
                    acc.z += wgt * ev.z; acc.w += wgt * ev.w;
                }
            }
            acc.x += __shfl_xor(acc.x, 32);
            acc.y += __shfl_xor(acc.y, 32);
            acc.z += __shfl_xor(acc.z, 32);
            acc.w += __shfl_xor(acc.w, 32);
            Z     += __shfl_xor(Z, 32);
            const float invZ = 1.0f / Z;
            acc.x *= invZ; acc.y *= invZ; acc.z *= invZ; acc.w *= invZ;
        }
        if (g == 0)
            *(float4*)&sE[w][c * 4] = acc;    // etilde (zeros if empty)
    }
    // no barrier: same-wave write->read

    // ---------------- out GEMM (wave-local) -> global ----------------------
    {
        const float4* Wb4 = (const float4*)Wt + (size_t)g * 64 * 32 + c;
        const float4* se4 = (const float4*)&sE[w][g * 64];
        float4 a = make_float4(0.f, 0.f, 0.f, 0.f);
#pragma unroll
        for (int b = 0; b < 4; ++b) {
            float4 m4[16];
#pragma unroll
            for (int k = 0; k < 16; ++k)
                m4[k] = Wb4[(size_t)(b * 16 + k) * 32];
            const float4 e0 = se4[b * 4 + 0];
            const float4 e1 = se4[b * 4 + 1];
            const float4 e2 = se4[b * 4 + 2];
            const float4 e3 = se4[b * 4 + 3];
            FMA4(a, e0.x, m4[0]);  FMA4(a, e0.y, m4[1]);
            FMA4(a, e0.z, m4[2]);  FMA4(a, e0.w, m4[3]);
            FMA4(a, e1.x, m4[4]);  FMA4(a, e1.y, m4[5]);
            FMA4(a, e1.z, m4[6]);  FMA4(a, e1.w, m4[7]);
            FMA4(a, e2.x, m4[8]);  FMA4(a, e2.y, m4[9]);
            FMA4(a, e2.z, m4[10]); FMA4(a, e2.w, m4[11]);
            FMA4(a, e3.x, m4[12]); FMA4(a, e3.y, m4[13]);
            FMA4(a, e3.z, m4[14]); FMA4(a, e3.w, m4[15]);
        }
        a.x += __shfl_xor(a.x, 32);
        a.y += __shfl_xor(a.y, 32);
        a.z += __shfl_xor(a.z, 32);
        a.w += __shfl_xor(a.w, 32);
        if (g == 0 && segi < S)
            *(float4*)&out[(size_t)segi * 128 + c * 4] = a;
    }
}

// ---------------------------------------------------------------------------
extern "C" void kernel_launch(void* const* d_in, const int* in_sizes, int n_in,
                              void* d_out, int out_size, void* d_ws, size_t ws_size,
                              hipStream_t stream) {
    const float* E   = (const float*)d_in[0];
    const int*   map = (const int*)d_in[1];
    const float* Wk  = (const float*)d_in[3];
    const float* Wv  = (const float*)d_in[4];
    const float* Wo  = (const float*)d_in[5];
    float* out = (float*)d_out;

    const int V = in_sizes[1];
    const int S = out_size / 128;

    char* p = (char*)d_ws;
    auto alloc = [&](size_t b) {
        char* r = p;
        p += (b + 255) & ~(size_t)255;
        return r;
    };
    int*   starts = (int*)alloc((size_t)(S + 1) * sizeof(int));
    float* M      = (float*)alloc(128 * 128 * sizeof(float));
    float* Wt     = (float*)alloc(128 * 128 * sizeof(float));

    k_segstarts<<<(V + 255) / 256, 256, 0, stream>>>(map, starts, V, S);
    k_prep<<<128, 128, 0, stream>>>(Wk, Wv, Wo, M, Wt);
    k_main<<<(S + G - 1) / G, 256, 0, stream>>>(E, starts, M, Wt, out, V, S);
}

// Round 11
// 222.255 us; speedup vs baseline: 1.2722x; 1.2722x over previous
//
#include <hip/hip_runtime.h>
#include <math.h>

#define G    4      // segments per block
#define CAP  96     // max staged rows per group (mean 80; ~4% fallback to HBM path)

// ---------------------------------------------------------------------------
__global__ void k_segstarts(const int* __restrict__ map, int* __restrict__ starts,
                            int V, int S) {
    int i = blockIdx.x * blockDim.x + threadIdx.x;
    if (i >= V) return;
    int cur  = map[i];
    int prev = (i == 0) ? -1 : map[i - 1];
    for (int s = prev + 1; s <= cur; ++s) starts[s] = i;
    if (i == V - 1) {
        for (int s = cur + 1; s <= S; ++s) starts[s] = V;
    }
}

__device__ __forceinline__ unsigned short f2bf(float x) {
    unsigned b = __float_as_uint(x);
    b += 0x7FFFu + ((b >> 16) & 1u);          // round-to-nearest-even
    return (unsigned short)(b >> 16);
}
__device__ __forceinline__ float bf2f(unsigned short u) {
    return __uint_as_float(((unsigned)u) << 16);
}

// M16[i][j] = bf16( sum_h Wk[h][i]*Wv[h][j] ) ;  Wt16[i][o] = bf16( Wo[o][i] )
__global__ void k_prep(const float* __restrict__ Wk, const float* __restrict__ Wv,
                       const float* __restrict__ Wo,
                       unsigned short* __restrict__ M16,
                       unsigned short* __restrict__ Wt16) {
    int i = blockIdx.x;
    int j = threadIdx.x;
    float acc = 0.f;
#pragma unroll 8
    for (int h = 0; h < 128; ++h)
        acc += Wk[h * 128 + i] * Wv[h * 128 + j];
    M16[i * 128 + j]  = f2bf(acc);
    Wt16[i * 128 + j] = f2bf(Wo[j * 128 + i]);
}

// ---------------------------------------------------------------------------
// k_main (R8 shell): one block = G consecutive segments = one contiguous fp32
// row range staged once in LDS. Phases (6 barriers):
//   stage -> mean -> qGEMM(part+final) -> attn -> outGEMM(part+final)
// GEMMs read bf16 M/Wt exactly ONCE per block (64 KB total vs R8's 256 KB):
// thread (j, ih) accumulates its 64-row i-half for ALL 4 segments; the two
// i-halves combine through sQ. sE reads are wave-uniform (LDS broadcast).
// ---------------------------------------------------------------------------
__global__ __launch_bounds__(256, 3) void k_main(
    const float* __restrict__ E, const int* __restrict__ starts,
    const unsigned short* __restrict__ M16, const unsigned short* __restrict__ Wt16,
    float* __restrict__ out, int V, int S)
{
    __shared__ float sA[CAP][128];   // 48 KB staged rows (fp32)
    __shared__ float sE[G][128];     // ebar, later etilde (2 KB)
    __shared__ float sQ[G][128];     // q; reused as GEMM partial buffer (2 KB)

    const int tid  = threadIdx.x;
    const int w    = tid >> 6;       // wave id = local segment id
    const int lane = tid & 63;
    const int s0   = blockIdx.x * G;

    const int se    = min(s0 + G, S);
    const int gr0   = starts[s0];
    const int nrows = starts[se] - gr0;
    const bool staged = (nrows <= CAP);

    const int c  = lane & 31;        // column quad (sweeps)
    const int g  = lane >> 5;        // row parity (sweeps)
    const int j  = tid & 127;        // GEMM output column
    const int ih = tid >> 7;         // GEMM i-half (0/1)

    // ---------------- stage: E rows -> LDS ---------------------------------
    if (staged && nrows > 0) {
        const int q4 = tid & 31;
        const int rr = tid >> 5;                 // 0..7, stride 8
        const float* gp = E + (size_t)gr0 * 128 + q4 * 4;
        float4 t[12];
#pragma unroll
        for (int k = 0; k < 12; ++k) {
            const int r = min(rr + k * 8, nrows - 1);   // clamp: benign dup
            t[k] = *(const float4*)(gp + (size_t)r * 128);
        }
#pragma unroll
        for (int k = 0; k < 12; ++k)
            *(float4*)&sA[rr + k * 8][q4 * 4] = t[k];   // dup rows unread
    }
    __syncthreads();                                            // B1

    // per-wave segment meta
    const int segi = s0 + w;
    int r0 = 0, n = 0, off = 0;
    if (segi < S) {
        r0  = starts[segi];
        n   = starts[segi + 1] - r0;
        off = r0 - gr0;
    }

    // ---------------- mean: ebar[w] ----------------------------------------
    {
        float4 sum = make_float4(0.f, 0.f, 0.f, 0.f);
        if (segi < S && n > 0) {
            if (staged) {
#pragma unroll 4
                for (int rp = 0; rp < n; rp += 2) {
                    const int row = rp + g;
                    const int rcl = min(row, n - 1);
                    const float4 ev = *(const float4*)&sA[off + rcl][c * 4];
                    const float m = (row < n) ? 1.f : 0.f;
                    sum.x += m * ev.x; sum.y += m * ev.y;
                    sum.z += m * ev.z; sum.w += m * ev.w;
                }
            } else {
                const float* bp = E + (size_t)r0 * 128 + c * 4;
#pragma unroll 4
                for (int rp = 0; rp < n; rp += 2) {
                    const int row = rp + g;
                    const int rcl = min(row, n - 1);
                    const float4 ev = *(const float4*)(bp + (size_t)rcl * 128);
                    const float m = (row < n) ? 1.f : 0.f;
                    sum.x += m * ev.x; sum.y += m * ev.y;
                    sum.z += m * ev.z; sum.w += m * ev.w;
                }
            }
            sum.x += __shfl_xor(sum.x, 32);
            sum.y += __shfl_xor(sum.y, 32);
            sum.z += __shfl_xor(sum.z, 32);
            sum.w += __shfl_xor(sum.w, 32);
            const float inv = 1.0f / (float)n;
            sum.x *= inv; sum.y *= inv; sum.z *= inv; sum.w *= inv;
        }
        if (g == 0)
            *(float4*)&sE[w][c * 4] = sum;    // zeros when segi>=S or n==0
    }
    __syncthreads();                                            // B2

    // ---------------- q GEMM: sQ = sE @ M16 (M read once per block) --------
    {
        const unsigned short* Mb = M16 + (size_t)(ih * 64) * 128 + j;
        float a0 = 0.f, a1 = 0.f, a2 = 0.f, a3 = 0.f;
        const float* e0 = &sE[0][ih * 64];
        const float* e1 = &sE[1][ih * 64];
        const float* e2 = &sE[2][ih * 64];
        const float* e3 = &sE[3][ih * 64];
#pragma unroll 16
        for (int i = 0; i < 64; ++i) {
            const float m = bf2f(Mb[(size_t)i * 128]);
            a0 += m * e0[i]; a1 += m * e1[i];
            a2 += m * e2[i]; a3 += m * e3[i];
        }
        if (ih == 1) {
            sQ[0][j] = a0; sQ[1][j] = a1; sQ[2][j] = a2; sQ[3][j] = a3;
        }
        __syncthreads();                                        // B3
        if (ih == 0) {
            sQ[0][j] += a0; sQ[1][j] += a1; sQ[2][j] += a2; sQ[3][j] += a3;
        }
    }
    __syncthreads();                                            // B4

    // ---------------- attn: merged scores + exp + weighted sum -------------
    {
        float4 acc = make_float4(0.f, 0.f, 0.f, 0.f);
        float Z = 0.f;
        if (segi < S && n > 0) {
            const float4 qv = *(const float4*)&sQ[w][c * 4];
            if (staged) {
#pragma unroll 4
                for (int rp = 0; rp < n; rp += 2) {
                    const int row = rp + g;
                    const int rcl = min(row, n - 1);
                    const float4 ev = *(const float4*)&sA[off + rcl][c * 4];
                    float pd = ev.x * qv.x + ev.y * qv.y
                             + ev.z * qv.z + ev.w * qv.w;
                    pd += __shfl_xor(pd, 1);
                    pd += __shfl_xor(pd, 2);
                    pd += __shfl_xor(pd, 4);
                    pd += __shfl_xor(pd, 8);
                    pd += __shfl_xor(pd, 16);
                    const float wgt = (row < n) ? __expf(pd) : 0.f;
                    Z += wgt;
                    acc.x += wgt * ev.x; acc.y += wgt * ev.y;
                    acc.z += wgt * ev.z; acc.w += wgt * ev.w;
                }
            } else {
                const float* bp = E + (size_t)r0 * 128 + c * 4;
#pragma unroll 4
                for (int rp = 0; rp < n; rp += 2) {
                    const int row = rp + g;
                    const int rcl = min(row, n - 1);
                    const float4 ev = *(const float4*)(bp + (size_t)rcl * 128);
                    float pd = ev.x * qv.x + ev.y * qv.y
                             + ev.z * qv.z + ev.w * qv.w;
                    pd += __shfl_xor(pd, 1);
                    pd += __shfl_xor(pd, 2);
                    pd += __shfl_xor(pd, 4);
                    pd += __shfl_xor(pd, 8);
                    pd += __shfl_xor(pd, 16);
                    const float wgt = (row < n) ? __expf(pd) : 0.f;
                    Z += wgt;
                    acc.x += wgt * ev.x; acc.y += wgt * ev.y;
                    acc.z += wgt * ev.z; acc.w += wgt * ev.w;
                }
            }
            acc.x += __shfl_xor(acc.x, 32);
            acc.y += __shfl_xor(acc.y, 32);
            acc.z += __shfl_xor(acc.z, 32);
            acc.w += __shfl_xor(acc.w, 32);
            Z     += __shfl_xor(Z, 32);
            const float invZ = 1.0f / Z;
            acc.x *= invZ; acc.y *= invZ; acc.z *= invZ; acc.w *= invZ;
        }
        if (g == 0)
            *(float4*)&sE[w][c * 4] = acc;    // etilde (zeros if empty)
    }
    __syncthreads();                                            // B5

    // ---------------- out GEMM: out = sE @ Wt16 (Wt read once per block) ---
    {
        const unsigned short* Wb = Wt16 + (size_t)(ih * 64) * 128 + j;
        float a0 = 0.f, a1 = 0.f, a2 = 0.f, a3 = 0.f;
        const float* e0 = &sE[0][ih * 64];
        const float* e1 = &sE[1][ih * 64];
        const float* e2 = &sE[2][ih * 64];
        const float* e3 = &sE[3][ih * 64];
#pragma unroll 16
        for (int i = 0; i < 64; ++i) {
            const float m = bf2f(Wb[(size_t)i * 128]);
            a0 += m * e0[i]; a1 += m * e1[i];
            a2 += m * e2[i]; a3 += m * e3[i];
        }
        if (ih == 1) {
            sQ[0][j] = a0; sQ[1][j] = a1; sQ[2][j] = a2; sQ[3][j] = a3;
        }
        __syncthreads();                                        // B6
        if (ih == 0) {
            if (s0 + 0 < S) out[(size_t)(s0 + 0) * 128 + j] = sQ[0][j] + a0;
            if (s0 + 1 < S) out[(size_t)(s0 + 1) * 128 + j] = sQ[1][j] + a1;
            if (s0 + 2 < S) out[(size_t)(s0 + 2) * 128 + j] = sQ[2][j] + a2;
            if (s0 + 3 < S) out[(size_t)(s0 + 3) * 128 + j] = sQ[3][j] + a3;
        }
    }
}

// ---------------------------------------------------------------------------
extern "C" void kernel_launch(void* const* d_in, const int* in_sizes, int n_in,
                              void* d_out, int out_size, void* d_ws, size_t ws_size,
                              hipStream_t stream) {
    const float* E   = (const float*)d_in[0];
    const int*   map = (const int*)d_in[1];
    const float* Wk  = (const float*)d_in[3];
    const float* Wv  = (const float*)d_in[4];
    const float* Wo  = (const float*)d_in[5];
    float* out = (float*)d_out;

    const int V = in_sizes[1];
    const int S = out_size / 128;

    char* p = (char*)d_ws;
    auto alloc = [&](size_t b) {
        char* r = p;
        p += (b + 255) & ~(size_t)255;
        return r;
    };
    int*            starts = (int*)alloc((size_t)(S + 1) * sizeof(int));
    unsigned short* M16    = (unsigned short*)alloc(128 * 128 * sizeof(unsigned short));
    unsigned short* Wt16   = (unsigned short*)alloc(128 * 128 * sizeof(unsigned short));

    k_segstarts<<<(V + 255) / 256, 256, 0, stream>>>(map, starts, V, S);
    k_prep<<<128, 128, 0, stream>>>(Wk, Wv, Wo, M16, Wt16);
    k_main<<<(S + G - 1) / G, 256, 0, stream>>>(E, starts, M16, Wt16, out, V, S);
}

// Round 12
// 196.645 us; speedup vs baseline: 1.4379x; 1.1302x over previous
//
#include <hip/hip_runtime.h>
#include <math.h>

#define G    4      // segments per block
#define CAP  96     // max staged rows per group (mean 80; ~4% fallback to HBM path)

// ---------------------------------------------------------------------------
__global__ void k_segstarts(const int* __restrict__ map, int* __restrict__ starts,
                            int V, int S) {
    int i = blockIdx.x * blockDim.x + threadIdx.x;
    if (i >= V) return;
    int cur  = map[i];
    int prev = (i == 0) ? -1 : map[i - 1];
    for (int s = prev + 1; s <= cur; ++s) starts[s] = i;
    if (i == V - 1) {
        for (int s = cur + 1; s <= S; ++s) starts[s] = V;
    }
}

__device__ __forceinline__ unsigned f2bf_rte(float x) {          // RTNE -> top 16
    unsigned b = __float_as_uint(x);
    b += 0x7FFFu + ((b >> 16) & 1u);
    return b >> 16;
}
__device__ __forceinline__ float bfu_lo(unsigned u) {            // low bf16
    return __uint_as_float(u << 16);
}
__device__ __forceinline__ float bfu_hi(unsigned u) {            // high bf16
    return __uint_as_float(u & 0xFFFF0000u);
}

// M16[i][j] = bf16( sum_h Wk[h][i]*Wv[h][j] ) ;  Wt16[i][o] = bf16( Wo[o][i] )
__global__ void k_prep(const float* __restrict__ Wk, const float* __restrict__ Wv,
                       const float* __restrict__ Wo,
                       unsigned short* __restrict__ M16,
                       unsigned short* __restrict__ Wt16) {
    int i = blockIdx.x;
    int j = threadIdx.x;
    float acc = 0.f;
#pragma unroll 8
    for (int h = 0; h < 128; ++h)
        acc += Wk[h * 128 + i] * Wv[h * 128 + j];
    M16[i * 128 + j]  = (unsigned short)f2bf_rte(acc);
    Wt16[i * 128 + j] = (unsigned short)f2bf_rte(Wo[j * 128 + i]);
}

// ---------------------------------------------------------------------------
// k_main: R11 structure with bf16 E-staging (LDS 28.7 KB -> 4 blocks/CU).
// Phases: stage -> mean -> qGEMM(once/block) -> attn -> outGEMM(once/block).
// Stage: 2 batches of 6 float4 loads (bounded register pressure, cf. R9 fail).
// ---------------------------------------------------------------------------
__global__ __launch_bounds__(256, 4) void k_main(
    const float* __restrict__ E, const int* __restrict__ starts,
    const unsigned short* __restrict__ M16, const unsigned short* __restrict__ Wt16,
    float* __restrict__ out, int V, int S)
{
    __shared__ unsigned sA[CAP][64];   // bf16-packed rows (24.6 KB)
    __shared__ float    sE[G][128];    // ebar, later etilde (2 KB)
    __shared__ float    sQ[G][128];    // q / GEMM partial buffer (2 KB)

    const int tid  = threadIdx.x;
    const int w    = tid >> 6;       // wave id = local segment id
    const int lane = tid & 63;
    const int s0   = blockIdx.x * G;

    const int se    = min(s0 + G, S);
    const int gr0   = starts[s0];
    const int nrows = starts[se] - gr0;
    const bool staged = (nrows <= CAP);

    const int c  = lane & 31;        // column quad (sweeps)
    const int g  = lane >> 5;        // row parity (sweeps)
    const int j  = tid & 127;        // GEMM output column
    const int ih = tid >> 7;         // GEMM i-half (0/1)

    // ---------------- stage: E rows -> bf16 LDS (2 batches of 6) -----------
    if (staged && nrows > 0) {
        const int q4 = tid & 31;
        const int rr = tid >> 5;                 // 0..7, stride 8
        const float* gp = E + (size_t)gr0 * 128 + q4 * 4;
#pragma unroll
        for (int b = 0; b < 2; ++b) {
            float4 t[6];
#pragma unroll
            for (int k = 0; k < 6; ++k) {
                const int r = min(rr + (b * 6 + k) * 8, nrows - 1);  // clamp: dup
                t[k] = *(const float4*)(gp + (size_t)r * 128);
            }
#pragma unroll
            for (int k = 0; k < 6; ++k) {
                uint2 u;
                u.x = f2bf_rte(t[k].x) | (f2bf_rte(t[k].y) << 16);
                u.y = f2bf_rte(t[k].z) | (f2bf_rte(t[k].w) << 16);
                *(uint2*)&sA[rr + (b * 6 + k) * 8][q4 * 2] = u;      // dup unread
            }
        }
    }
    __syncthreads();                                            // B1

    // per-wave segment meta
    const int segi = s0 + w;
    int r0 = 0, n = 0, off = 0;
    if (segi < S) {
        r0  = starts[segi];
        n   = starts[segi + 1] - r0;
        off = r0 - gr0;
    }

    // ---------------- mean: ebar[w] ----------------------------------------
    {
        float4 sum = make_float4(0.f, 0.f, 0.f, 0.f);
        if (segi < S && n > 0) {
            if (staged) {
#pragma unroll 4
                for (int rp = 0; rp < n; rp += 2) {
                    const int row = rp + g;
                    const int rcl = min(row, n - 1);
                    const uint2 u = *(const uint2*)&sA[off + rcl][c * 2];
                    const float m = (row < n) ? 1.f : 0.f;
                    sum.x += m * bfu_lo(u.x); sum.y += m * bfu_hi(u.x);
                    sum.z += m * bfu_lo(u.y); sum.w += m * bfu_hi(u.y);
                }
            } else {
                const float* bp = E + (size_t)r0 * 128 + c * 4;
#pragma unroll 4
                for (int rp = 0; rp < n; rp += 2) {
                    const int row = rp + g;
                    const int rcl = min(row, n - 1);
                    const float4 ev = *(const float4*)(bp + (size_t)rcl * 128);
                    const float m = (row < n) ? 1.f : 0.f;
                    sum.x += m * ev.x; sum.y += m * ev.y;
                    sum.z += m * ev.z; sum.w += m * ev.w;
                }
            }
            sum.x += __shfl_xor(sum.x, 32);
            sum.y += __shfl_xor(sum.y, 32);
            sum.z += __shfl_xor(sum.z, 32);
            sum.w += __shfl_xor(sum.w, 32);
            const float inv = 1.0f / (float)n;
            sum.x *= inv; sum.y *= inv; sum.z *= inv; sum.w *= inv;
        }
        if (g == 0)
            *(float4*)&sE[w][c * 4] = sum;    // zeros when segi>=S or n==0
    }
    __syncthreads();                                            // B2

    // ---------------- q GEMM: sQ = sE @ M16 (M read once per block) --------
    {
        const unsigned short* Mb = M16 + (size_t)(ih * 64) * 128 + j;
        float a0 = 0.f, a1 = 0.f, a2 = 0.f, a3 = 0.f;
        const float* e0 = &sE[0][ih * 64];
        const float* e1 = &sE[1][ih * 64];
        const float* e2 = &sE[2][ih * 64];
        const float* e3 = &sE[3][ih * 64];
#pragma unroll 16
        for (int i = 0; i < 64; ++i) {
            const float m = bfu_lo((unsigned)Mb[(size_t)i * 128] << 16 >> 16);
            const float mm = __uint_as_float(((unsigned)Mb[(size_t)i * 128]) << 16);
            (void)m;
            a0 += mm * e0[i]; a1 += mm * e1[i];
            a2 += mm * e2[i]; a3 += mm * e3[i];
        }
        if (ih == 1) {
            sQ[0][j] = a0; sQ[1][j] = a1; sQ[2][j] = a2; sQ[3][j] = a3;
        }
        __syncthreads();                                        // B3
        if (ih == 0) {
            sQ[0][j] += a0; sQ[1][j] += a1; sQ[2][j] += a2; sQ[3][j] += a3;
        }
    }
    __syncthreads();                                            // B4

    // ---------------- attn: merged scores + exp + weighted sum -------------
    {
        float4 acc = make_float4(0.f, 0.f, 0.f, 0.f);
        float Z = 0.f;
        if (segi < S && n > 0) {
            const float4 qv = *(const float4*)&sQ[w][c * 4];
            if (staged) {
#pragma unroll 4
                for (int rp = 0; rp < n; rp += 2) {
                    const int row = rp + g;
                    const int rcl = min(row, n - 1);
                    const uint2 u = *(const uint2*)&sA[off + rcl][c * 2];
                    const float e0 = bfu_lo(u.x), e1 = bfu_hi(u.x);
                    const float e2 = bfu_lo(u.y), e3 = bfu_hi(u.y);
                    float pd = e0 * qv.x + e1 * qv.y + e2 * qv.z + e3 * qv.w;
                    pd += __shfl_xor(pd, 1);
                    pd += __shfl_xor(pd, 2);
                    pd += __shfl_xor(pd, 4);
                    pd += __shfl_xor(pd, 8);
                    pd += __shfl_xor(pd, 16);
                    const float wgt = (row < n) ? __expf(pd) : 0.f;
                    Z += wgt;
                    acc.x += wgt * e0; acc.y += wgt * e1;
                    acc.z += wgt * e2; acc.w += wgt * e3;
                }
            } else {
                const float* bp = E + (size_t)r0 * 128 + c * 4;
#pragma unroll 4
                for (int rp = 0; rp < n; rp += 2) {
                    const int row = rp + g;
                    const int rcl = min(row, n - 1);
                    const float4 ev = *(const float4*)(bp + (size_t)rcl * 128);
                    float pd = ev.x * qv.x + ev.y * qv.y
                             + ev.z * qv.z + ev.w * qv.w;
                    pd += __shfl_xor(pd, 1);
                    pd += __shfl_xor(pd, 2);
                    pd += __shfl_xor(pd, 4);
                    pd += __shfl_xor(pd, 8);
                    pd += __shfl_xor(pd, 16);
                    const float wgt = (row < n) ? __expf(pd) : 0.f;
                    Z += wgt;
                    acc.x += wgt * ev.x; acc.y += wgt * ev.y;
                    acc.z += wgt * ev.z; acc.w += wgt * ev.w;
                }
            }
            acc.x += __shfl_xor(acc.x, 32);
            acc.y += __shfl_xor(acc.y, 32);
            acc.z += __shfl_xor(acc.z, 32);
            acc.w += __shfl_xor(acc.w, 32);
            Z     += __shfl_xor(Z, 32);
            const float invZ = 1.0f / Z;
            acc.x *= invZ; acc.y *= invZ; acc.z *= invZ; acc.w *= invZ;
        }
        if (g == 0)
            *(float4*)&sE[w][c * 4] = acc;    // etilde (zeros if empty)
    }
    __syncthreads();                                            // B5

    // ---------------- out GEMM: out = sE @ Wt16 (Wt read once per block) ---
    {
        const unsigned short* Wb = Wt16 + (size_t)(ih * 64) * 128 + j;
        float a0 = 0.f, a1 = 0.f, a2 = 0.f, a3 = 0.f;
        const float* e0 = &sE[0][ih * 64];
        const float* e1 = &sE[1][ih * 64];
        const float* e2 = &sE[2][ih * 64];
        const float* e3 = &sE[3][ih * 64];
#pragma unroll 16
        for (int i = 0; i < 64; ++i) {
            const float m = __uint_as_float(((unsigned)Wb[(size_t)i * 128]) << 16);
            a0 += m * e0[i]; a1 += m * e1[i];
            a2 += m * e2[i]; a3 += m * e3[i];
        }
        if (ih == 1) {
            sQ[0][j] = a0; sQ[1][j] = a1; sQ[2][j] = a2; sQ[3][j] = a3;
        }
        __syncthreads();                                        // B6
        if (ih == 0) {
            if (s0 + 0 < S) out[(size_t)(s0 + 0) * 128 + j] = sQ[0][j] + a0;
            if (s0 + 1 < S) out[(size_t)(s0 + 1) * 128 + j] = sQ[1][j] + a1;
            if (s0 + 2 < S) out[(size_t)(s0 + 2) * 128 + j] = sQ[2][j] + a2;
            if (s0 + 3 < S) out[(size_t)(s0 + 3) * 128 + j] = sQ[3][j] + a3;
        }
    }
}

// ---------------------------------------------------------------------------
extern "C" void kernel_launch(void* const* d_in, const int* in_sizes, int n_in,
                              void* d_out, int out_size, void* d_ws, size_t ws_size,
                              hipStream_t stream) {
    const float* E   = (const float*)d_in[0];
    const int*   map = (const int*)d_in[1];
    const float* Wk  = (const float*)d_in[3];
    const float* Wv  = (const float*)d_in[4];
    const float* Wo  = (const float*)d_in[5];
    float* out = (float*)d_out;

    const int V = in_sizes[1];
    const int S = out_size / 128;

    char* p = (char*)d_ws;
    auto alloc = [&](size_t b) {
        char* r = p;
        p += (b + 255) & ~(size_t)255;
        return r;
    };
    int*            starts = (int*)alloc((size_t)(S + 1) * sizeof(int));
    unsigned short* M16    = (unsigned short*)alloc(128 * 128 * sizeof(unsigned short));
    unsigned short* Wt16   = (unsigned short*)alloc(128 * 128 * sizeof(unsigned short));

    k_segstarts<<<(V + 255) / 256, 256, 0, stream>>>(map, starts, V, S);
    k_prep<<<128, 128, 0, stream>>>(Wk, Wv, Wo, M16, Wt16);
    k_main<<<(S + G - 1) / G, 256, 0, stream>>>(E, starts, M16, Wt16, out, V, S);
}